// Round 4
// baseline (35.798 us; speedup 1.0000x reference)
//
#include <hip/hip_runtime.h>
#include <math.h>

// Problem constants (fixed by the reference setup)
#define NN 16
#define CC 85
#define HH 160
#define WW 160
#define HW_ 25600            // H*W
#define NHW 409600           // N*H*W
#define TB 256
#define GRIDN 100            // 100 blocks * 256 thr = 25600 threads
#define TTOT (GRIDN * TB)    // 25600; cells: 16/thread, anchors: <=1/thread

struct Sync {                 // zeroed by hipMemsetAsync every call
  double sum_liou;
  double sum_nll;
  double obj_corr;
  int cnt_f;
  int nperb[NN];
  int c1, c2, cdone;
};

__device__ __forceinline__ float wave_sum(float v) {
#pragma unroll
  for (int o = 32; o; o >>= 1) v += __shfl_down(v, o, 64);
  return v;
}

__device__ __forceinline__ float sl1(float d) {
  float ad = fabsf(d);
  return (ad < 1.f) ? 0.5f * d * d : (ad - 0.5f);
}

// SIoU variant from the reference (_bbox_iou)
__device__ __forceinline__ float siou(float pcx, float pcy, float pw, float ph,
                                      float gcx, float gcy, float gw, float gh) {
  const float eps = 1e-7f;
  float b1x1 = pcx - pw * 0.5f, b1x2 = pcx + pw * 0.5f;
  float b1y1 = pcy - ph * 0.5f, b1y2 = pcy + ph * 0.5f;
  float b2x1 = gcx - gw * 0.5f, b2x2 = gcx + gw * 0.5f;
  float b2y1 = gcy - gh * 0.5f, b2y2 = gcy + gh * 0.5f;
  float inter = fmaxf(fminf(b1x2, b2x2) - fmaxf(b1x1, b2x1), 0.f) *
                fmaxf(fminf(b1y2, b2y2) - fmaxf(b1y1, b2y1), 0.f);
  float w1 = b1x2 - b1x1, h1 = b1y2 - b1y1 + eps;
  float w2 = b2x2 - b2x1, h2 = b2y2 - b2y1 + eps;
  float uni = w1 * h1 + w2 * h2 - inter + eps;
  float iou = inter / uni;
  float cw = fmaxf(b1x2, b2x2) - fminf(b1x1, b2x1);
  float ch = fmaxf(b1y2, b2y2) - fminf(b1y1, b2y1);
  float s_cw = (b2x1 + b2x2 - b1x1 - b1x2) * 0.5f;
  float s_ch = (b2y1 + b2y2 - b1y1 - b1y2) * 0.5f;
  float sigma = sqrtf(s_cw * s_cw + s_ch * s_ch);
  float sin_a1 = fabsf(s_cw) / sigma;
  float sin_a2 = fabsf(s_ch) / sigma;
  float sin_a = (sin_a1 > 0.70710678f) ? sin_a2 : sin_a1;
  // cos(2*asin(x) - pi/2) == 2*x*sqrt(1-x^2)
  float angle_cost = 2.f * sin_a * sqrtf(fmaxf(1.f - sin_a * sin_a, 0.f));
  float rx = s_cw / cw; rx *= rx;
  float ry = s_ch / ch; ry *= ry;
  float gamma = angle_cost - 2.f;
  float dist = 2.f - expf(gamma * rx) - expf(gamma * ry);
  float ow = fabsf(w1 - w2) / fmaxf(w1, w2);
  float oh = fabsf(h1 - h2) / fmaxf(h1, h2);
  float e1 = 1.f - expf(-ow), e2 = 1.f - expf(-oh);
  float s1 = e1 * e1; s1 *= s1;
  float s2 = e2 * e2; s2 *= s2;
  return iou - 0.5f * (dist + s1 + s2);
}

// release-inc + acquire-spin grid barrier; GRIDN=100 blocks << 256 CUs so all
// blocks are co-resident (each block is 4 waves; no occupancy limiter).
__device__ __forceinline__ void grid_barrier(int* c, int target) {
  __syncthreads();
  if (threadIdx.x == 0) {
    __threadfence();
    __hip_atomic_fetch_add(c, 1, __ATOMIC_RELEASE, __HIP_MEMORY_SCOPE_AGENT);
    while (__hip_atomic_load(c, __ATOMIC_ACQUIRE, __HIP_MEMORY_SCOPE_AGENT) < target)
      __builtin_amdgcn_s_sleep(1);
  }
  __syncthreads();
}

__global__ __launch_bounds__(TB, 1)
void fused(const float* __restrict__ preds, const float* __restrict__ targets,
           int M, Sync* __restrict__ sy, int* __restrict__ winner,
           float* __restrict__ part_obj, float* __restrict__ part_iou,
           float* __restrict__ part_cnt, float* __restrict__ out) {
  const int tid = threadIdx.x, bid = blockIdx.x;
  const int t = bid * TB + tid;
  const int lane = tid & 63, wid = tid >> 6;
  const int M4 = 4 * M;

  __shared__ float shA0[4], shA1[4], shA2[4];
  __shared__ float shM0[4], shM1[4], shO[4];
  __shared__ float shB0[4], shB1[4], shB2[4];
  __shared__ float shC0[4];
  __shared__ int hist[NN];

  // ======== Phase A: winner init + base obj partial + anchor SIoU ========
  float objs = 0.f;
#pragma unroll
  for (int i = 0; i < 4; ++i) {
    int i0 = (t + i * TTOT) * 4;                 // coalesced 16B per lane
    *reinterpret_cast<int4*>(winner + i0) = make_int4(-1, -1, -1, -1);
    int b = i0 / HW_;
    int r = i0 - b * HW_;                        // HW_ % 4 == 0
    float4 p4 = *reinterpret_cast<const float4*>(preds + (size_t)b * CC * HW_ + r);
    objs += sl1(p4.x) + sl1(p4.y) + sl1(p4.z) + sl1(p4.w);
  }

  // anchor state lives in registers for the whole kernel
  float iou_v = 0.f, mf = 0.f, p_obj = 0.f;
  int ab = 0, acls = 0, agi = 0, agj = 0;
  bool am = false;
  if (t < M4) {
    int mm = t % M, q = t / M;
    const float* t6 = targets + (size_t)mm * 6;
    ab = (int)t6[0];
    acls = (int)t6[1];
    float gx = t6[2] * (float)WW, gy = t6[3] * (float)HH;
    float gw = t6[4] * (float)WW, gh = t6[5] * (float)HH;
    agi = (int)gx + (q & 1);
    agj = (int)gy + (q >> 1);
    am = (agi >= 1) && (agi < WW) && (agj >= 1) && (agj < HH);
    if (am) {
      const float* p = preds + (size_t)ab * CC * HW_ + (size_t)agj * WW + agi;
      p_obj = p[0];
      float p0 = p[(size_t)1 * HW_];
      float p1 = p[(size_t)2 * HW_];
      float p2 = p[(size_t)3 * HW_];
      float p3 = p[(size_t)4 * HW_];
      float px = tanhf(p0) + (float)agi;
      float py = tanhf(p1) + (float)agj;
      float pw = (1.f / (1.f + expf(-p2))) * (float)WW;
      float ph = (1.f / (1.f + expf(-p3))) * (float)HH;
      iou_v = siou(px, py, pw, ph, gx, gy, gw, gh);
      mf = 1.f;
    }
  }

  {
    float o = wave_sum(objs), s = wave_sum(iou_v), c = wave_sum(mf);
    if (lane == 0) { shA0[wid] = o; shA1[wid] = s; shA2[wid] = c; }
    __syncthreads();
    if (tid == 0) {
      part_obj[bid] = shA0[0] + shA0[1] + shA0[2] + shA0[3];
      part_iou[bid] = shA1[0] + shA1[1] + shA1[2] + shA1[3];
      part_cnt[bid] = shA2[0] + shA2[1] + shA2[2] + shA2[3];
    }
  }

  grid_barrier(&sy->c1, GRIDN);

  // ======== Phase B: iou_mean + filter + nll + winner atomicMax + nperb ====
  const bool active = (bid * TB) < M4;     // uniform per block
  float obj_base = 0.f;
  bool af = false; int aidx = 0;
  if (active) {
    if (tid < NN) hist[tid] = 0;
    float ssum = (tid < GRIDN) ? part_iou[tid] : 0.f;
    float csum = (tid < GRIDN) ? part_cnt[tid] : 0.f;
    ssum = wave_sum(ssum); csum = wave_sum(csum);
    if (lane == 0) { shM0[wid] = ssum; shM1[wid] = csum; }
    __syncthreads();
    float iou_mean = (shM0[0] + shM0[1] + shM0[2] + shM0[3]) /
                     fmaxf(shM1[0] + shM1[1] + shM1[2] + shM1[3], 1.f);

    if (bid == 0) {    // block 0 also folds the base-obj partials
      float v = (tid < GRIDN) ? part_obj[tid] : 0.f;
      v = wave_sum(v);
      if (lane == 0) shO[wid] = v;
      __syncthreads();
      obj_base = shO[0] + shO[1] + shO[2] + shO[3];
    }

    float fc = 0.f, liou = 0.f, nllv = 0.f;
    if (am && iou_v > iou_mean) {
      af = true;
      fc = 1.f;
      liou = 1.f - iou_v;
      nllv = -logf(preds[(size_t)(ab * CC + 5 + acls) * HW_ + (size_t)agj * WW + agi]);
      aidx = ab * HW_ + agj * WW + agi;
      atomicMax(&winner[aidx], t);   // max-t == numpy last-occurrence-wins
      atomicAdd(&hist[ab], 1);
    }
    float a = wave_sum(fc), b2 = wave_sum(liou), d2 = wave_sum(nllv);
    if (lane == 0) { shB0[wid] = a; shB1[wid] = b2; shB2[wid] = d2; }
    __syncthreads();
    if (tid == 0) {
      atomicAdd(&sy->cnt_f, (int)(shB0[0] + shB0[1] + shB0[2] + shB0[3]));
      atomicAdd(&sy->sum_liou, (double)(shB1[0] + shB1[1] + shB1[2] + shB1[3]));
      atomicAdd(&sy->sum_nll, (double)(shB2[0] + shB2[1] + shB2[2] + shB2[3]));
    }
    if (tid < NN && hist[tid] > 0)
      atomicAdd(&sy->nperb[tid], hist[tid]);
  }

  grid_barrier(&sy->c2, GRIDN);

  // ======== Phase C: winner correction (no preds re-read) ========
  if (active) {
    float corr = 0.f;
    if (af && winner[aidx] == t) {
      float fval = (float)HW_ / (float)sy->nperb[ab] * 0.25f;
      corr = sl1(p_obj - iou_v) * fval - sl1(p_obj) * 0.75f;
    }
    float r = wave_sum(corr);
    if (lane == 0) shC0[wid] = r;
    __syncthreads();
    if (tid == 0)
      atomicAdd(&sy->obj_corr, (double)(shC0[0] + shC0[1] + shC0[2] + shC0[3]));
  }

  // ======== exit protocol: done-counter; block 0 thread 0 finalizes ========
  __syncthreads();
  if (tid == 0) {
    __threadfence();
    __hip_atomic_fetch_add(&sy->cdone, 1, __ATOMIC_RELEASE, __HIP_MEMORY_SCOPE_AGENT);
    if (bid == 0) {
      while (__hip_atomic_load(&sy->cdone, __ATOMIC_ACQUIRE, __HIP_MEMORY_SCOPE_AGENT) < GRIDN)
        __builtin_amdgcn_s_sleep(1);
      float cf = fmaxf((float)sy->cnt_f, 1.f);
      float iou_loss = (float)sy->sum_liou / cf;
      float cls_loss = (float)sy->sum_nll / cf;
      float obj_loss = (float)((0.75 * (double)obj_base + sy->obj_corr) / (double)NHW);
      out[0] = iou_loss;
      out[1] = obj_loss;
      out[2] = cls_loss;
      out[3] = iou_loss * 8.f + obj_loss * 16.f + cls_loss;
    }
  }
}

extern "C" void kernel_launch(void* const* d_in, const int* in_sizes, int n_in,
                              void* d_out, int out_size, void* d_ws, size_t ws_size,
                              hipStream_t stream) {
  const float* preds = (const float*)d_in[0];
  const float* targets = (const float*)d_in[1];
  int M = in_sizes[1] / 6;     // 4096

  char* ws = (char*)d_ws;
  Sync* sy = (Sync*)ws;                                   // 256 B (memset)
  int* winner = (int*)(ws + 256);                         // 1.6 MB
  float* part_obj = (float*)(ws + 256 + (size_t)NHW * 4); // 512 B each
  float* part_iou = part_obj + 128;
  float* part_cnt = part_iou + 128;

  // d_ws is poisoned to 0xAA before timing; the sync block must start at 0
  // every call (counters can't self-reset safely across graph replays).
  hipMemsetAsync(ws, 0, 256, stream);
  fused<<<GRIDN, TB, 0, stream>>>(preds, targets, M, sy, winner,
                                  part_obj, part_iou, part_cnt, (float*)d_out);
}

// Round 5
// 21.081 us; speedup vs baseline: 1.6981x; 1.6981x over previous
//
#include <hip/hip_runtime.h>
#include <math.h>

// Problem constants (fixed by the reference setup)
#define NN 16
#define CC 85
#define HH 160
#define WW 160
#define HW_ 25600            // H*W
#define NHW 409600           // N*H*W
#define TB 256
#define GRID1 400            // K1: NHW/4/TB = 400 (one float4 cell per thread)
#define GRID2 64             // K2: M4/TB = 64 (M=4096)

struct Sync {                // zeroed by K1 thread 0 every call
  double sum_liou;
  double sum_nll;
  double obj_corr;
  int cnt_f;
  int c1, cdone;
  int nperb[NN];
};

__device__ __forceinline__ float wave_sum(float v) {
#pragma unroll
  for (int o = 32; o; o >>= 1) v += __shfl_down(v, o, 64);
  return v;
}

__device__ __forceinline__ float sl1(float d) {
  float ad = fabsf(d);
  return (ad < 1.f) ? 0.5f * d * d : (ad - 0.5f);
}

// SIoU variant from the reference (_bbox_iou)
__device__ __forceinline__ float siou(float pcx, float pcy, float pw, float ph,
                                      float gcx, float gcy, float gw, float gh) {
  const float eps = 1e-7f;
  float b1x1 = pcx - pw * 0.5f, b1x2 = pcx + pw * 0.5f;
  float b1y1 = pcy - ph * 0.5f, b1y2 = pcy + ph * 0.5f;
  float b2x1 = gcx - gw * 0.5f, b2x2 = gcx + gw * 0.5f;
  float b2y1 = gcy - gh * 0.5f, b2y2 = gcy + gh * 0.5f;
  float inter = fmaxf(fminf(b1x2, b2x2) - fmaxf(b1x1, b2x1), 0.f) *
                fmaxf(fminf(b1y2, b2y2) - fmaxf(b1y1, b2y1), 0.f);
  float w1 = b1x2 - b1x1, h1 = b1y2 - b1y1 + eps;
  float w2 = b2x2 - b2x1, h2 = b2y2 - b2y1 + eps;
  float uni = w1 * h1 + w2 * h2 - inter + eps;
  float iou = inter / uni;
  float cw = fmaxf(b1x2, b2x2) - fminf(b1x1, b2x1);
  float ch = fmaxf(b1y2, b2y2) - fminf(b1y1, b2y1);
  float s_cw = (b2x1 + b2x2 - b1x1 - b1x2) * 0.5f;
  float s_ch = (b2y1 + b2y2 - b1y1 - b1y2) * 0.5f;
  float sigma = sqrtf(s_cw * s_cw + s_ch * s_ch);
  float sin_a1 = fabsf(s_cw) / sigma;
  float sin_a2 = fabsf(s_ch) / sigma;
  float sin_a = (sin_a1 > 0.70710678f) ? sin_a2 : sin_a1;
  // cos(2*asin(x) - pi/2) == 2*x*sqrt(1-x^2)
  float angle_cost = 2.f * sin_a * sqrtf(fmaxf(1.f - sin_a * sin_a, 0.f));
  float rx = s_cw / cw; rx *= rx;
  float ry = s_ch / ch; ry *= ry;
  float gamma = angle_cost - 2.f;
  float dist = 2.f - expf(gamma * rx) - expf(gamma * ry);
  float ow = fabsf(w1 - w2) / fmaxf(w1, w2);
  float oh = fabsf(h1 - h2) / fmaxf(h1, h2);
  float e1 = 1.f - expf(-ow), e2 = 1.f - expf(-oh);
  float s1 = e1 * e1; s1 *= s1;
  float s2 = e2 * e2; s2 *= s2;
  return iou - 0.5f * (dist + s1 + s2);
}

// K1 (grid 400, high TLP): Sync zero + base-obj partial + all anchor gathers
// + SIoU + scatter winner init. Heavy memory work lives here.
__global__ __launch_bounds__(TB)
void k1(const float* __restrict__ preds, const float* __restrict__ targets,
        int M, Sync* __restrict__ sy, int* __restrict__ winner,
        float* __restrict__ iou_arr, int* __restrict__ meta_arr,
        float* __restrict__ pobj_arr, float* __restrict__ nll_arr,
        float* __restrict__ part_obj, float* __restrict__ part_iou,
        float* __restrict__ part_cnt) {
  const int tid = threadIdx.x, bid = blockIdx.x;
  const int t = bid * TB + tid;
  const int lane = tid & 63, wid = tid >> 6;

  if (t == 0) {
    sy->sum_liou = 0.0; sy->sum_nll = 0.0; sy->obj_corr = 0.0;
    sy->cnt_f = 0; sy->c1 = 0; sy->cdone = 0;
    for (int b = 0; b < NN; ++b) sy->nperb[b] = 0;
  }

  // --- one float4 cell per thread: base obj term (tobj=0 case) ---
  float objs;
  {
    int i0 = t * 4;
    int b = i0 / HW_;
    int r = i0 - b * HW_;                        // HW_ % 4 == 0
    float4 p4 = *reinterpret_cast<const float4*>(preds + (size_t)b * CC * HW_ + r);
    objs = sl1(p4.x) + sl1(p4.y) + sl1(p4.z) + sl1(p4.w);
  }

  // --- anchors (first 64 blocks): decode + 6 gathers + SIoU ---
  const int M4 = 4 * M;
  float iou_v = 0.f, mf = 0.f;
  if (t < M4) {
    int mm = t % M, q = t / M;
    const float* t6 = targets + (size_t)mm * 6;
    int ab = (int)t6[0];
    int acls = (int)t6[1];
    float gx = t6[2] * (float)WW, gy = t6[3] * (float)HH;
    float gw = t6[4] * (float)WW, gh = t6[5] * (float)HH;
    int gi = (int)gx + (q & 1);
    int gj = (int)gy + (q >> 1);
    bool m = (gi >= 1) && (gi < WW) && (gj >= 1) && (gj < HH);
    int meta = 0;
    float pobj = 0.f, nllv = 0.f;
    if (m) {
      const float* p = preds + (size_t)ab * CC * HW_ + (size_t)gj * WW + gi;
      pobj = p[0];
      float p1 = p[(size_t)1 * HW_];
      float p2 = p[(size_t)2 * HW_];
      float p3 = p[(size_t)3 * HW_];
      float p4v = p[(size_t)4 * HW_];
      float pc = p[(size_t)(5 + acls) * HW_];
      float px = tanhf(p1) + (float)gi;
      float py = tanhf(p2) + (float)gj;
      float pw = (1.f / (1.f + expf(-p3))) * (float)WW;
      float ph = (1.f / (1.f + expf(-p4v))) * (float)HH;
      iou_v = siou(px, py, pw, ph, gx, gy, gw, gh);
      nllv = -logf(pc);
      mf = 1.f;
      int aidx = ab * HW_ + gj * WW + gi;
      winner[aidx] = -1;                  // scatter init: only used cells
      meta = 1 | (ab << 1) | (aidx << 5); // aidx < 2^19 -> meta < 2^24
    }
    iou_arr[t] = iou_v;
    meta_arr[t] = meta;
    pobj_arr[t] = pobj;
    nll_arr[t] = nllv;
  }

  __shared__ float shO[4], shI[4], shC[4];
  float o = wave_sum(objs), s = wave_sum(iou_v), c = wave_sum(mf);
  if (lane == 0) { shO[wid] = o; shI[wid] = s; shC[wid] = c; }
  __syncthreads();
  if (tid == 0) {
    part_obj[bid] = shO[0] + shO[1] + shO[2] + shO[3];
    part_iou[bid] = shI[0] + shI[1] + shI[2] + shI[3];
    part_cnt[bid] = shC[0] + shC[1] + shC[2] + shC[3];
  }
}

// K2 (grid 64, co-resident): filter + atomics + winner max | barrier |
// correction + finalize. Zero preds access.
__global__ __launch_bounds__(TB)
void k2(Sync* __restrict__ sy, int* __restrict__ winner,
        const float* __restrict__ iou_arr, const int* __restrict__ meta_arr,
        const float* __restrict__ pobj_arr, const float* __restrict__ nll_arr,
        const float* __restrict__ part_obj, const float* __restrict__ part_iou,
        const float* __restrict__ part_cnt, int M, float* __restrict__ out) {
  const int tid = threadIdx.x, bid = blockIdx.x;
  const int t = bid * TB + tid;
  const int lane = tid & 63, wid = tid >> 6;
  const int M4 = 4 * M;

  __shared__ float shS[4], shC[4], shO[4];
  __shared__ float shA[4], shB[4], shD[4], shR[4];
  __shared__ int hist[NN];
  if (tid < NN) hist[tid] = 0;

  // iou_mean: fixed-order reduce of 400 partials (identical in every block)
  float s = 0.f, c = 0.f;
  for (int i = tid; i < GRID1; i += TB) { s += part_iou[i]; c += part_cnt[i]; }
  s = wave_sum(s); c = wave_sum(c);
  if (lane == 0) { shS[wid] = s; shC[wid] = c; }
  __syncthreads();
  float iou_mean = (shS[0] + shS[1] + shS[2] + shS[3]) /
                   fmaxf(shC[0] + shC[1] + shC[2] + shC[3], 1.f);

  float obj_base = 0.f;
  if (bid == 0) {
    float v = 0.f;
    for (int i = tid; i < GRID1; i += TB) v += part_obj[i];
    v = wave_sum(v);
    if (lane == 0) shO[wid] = v;
    __syncthreads();
    obj_base = shO[0] + shO[1] + shO[2] + shO[3];
  }

  // per-anchor state (all streaming reads)
  bool af = false;
  int ab = 0, aidx = 0;
  float iou_v = 0.f, pobj = 0.f;
  float fc = 0.f, liou = 0.f, nl = 0.f;
  if (t < M4) {
    int meta = meta_arr[t];
    iou_v = iou_arr[t];
    pobj = pobj_arr[t];
    float nllv = nll_arr[t];
    bool am = (meta & 1);
    ab = (meta >> 1) & 15;
    aidx = meta >> 5;
    if (am && iou_v > iou_mean) {
      af = true;
      fc = 1.f;
      liou = 1.f - iou_v;
      nl = nllv;
      atomicMax(&winner[aidx], t);   // max-t == numpy last-occurrence-wins
      atomicAdd(&hist[ab], 1);
    }
  }
  float a = wave_sum(fc), b2 = wave_sum(liou), d2 = wave_sum(nl);
  if (lane == 0) { shA[wid] = a; shB[wid] = b2; shD[wid] = d2; }
  __syncthreads();
  if (tid == 0) {
    atomicAdd(&sy->cnt_f, (int)(shA[0] + shA[1] + shA[2] + shA[3]));
    atomicAdd(&sy->sum_liou, (double)(shB[0] + shB[1] + shB[2] + shB[3]));
    atomicAdd(&sy->sum_nll, (double)(shD[0] + shD[1] + shD[2] + shD[3]));
  }
  if (tid < NN && hist[tid] > 0)
    atomicAdd(&sy->nperb[tid], hist[tid]);

  // ---- grid barrier over 64 blocks (all co-resident: 64 << 256 CUs) ----
  __syncthreads();
  if (tid == 0) {
    __threadfence();
    __hip_atomic_fetch_add(&sy->c1, 1, __ATOMIC_RELEASE, __HIP_MEMORY_SCOPE_AGENT);
    while (__hip_atomic_load(&sy->c1, __ATOMIC_ACQUIRE, __HIP_MEMORY_SCOPE_AGENT) < GRID2)
      __builtin_amdgcn_s_sleep(1);
  }
  __syncthreads();

  // ---- correction (winner check), then finalize in block 0 ----
  float corr = 0.f;
  if (af && winner[aidx] == t) {
    float fval = (float)HW_ / (float)sy->nperb[ab] * 0.25f;
    corr = sl1(pobj - iou_v) * fval - sl1(pobj) * 0.75f;
  }
  float r = wave_sum(corr);
  if (lane == 0) shR[wid] = r;
  __syncthreads();
  if (tid == 0) {
    atomicAdd(&sy->obj_corr, (double)(shR[0] + shR[1] + shR[2] + shR[3]));
    __threadfence();
    __hip_atomic_fetch_add(&sy->cdone, 1, __ATOMIC_RELEASE, __HIP_MEMORY_SCOPE_AGENT);
    if (bid == 0) {
      while (__hip_atomic_load(&sy->cdone, __ATOMIC_ACQUIRE, __HIP_MEMORY_SCOPE_AGENT) < GRID2)
        __builtin_amdgcn_s_sleep(1);
      float cf = fmaxf((float)sy->cnt_f, 1.f);
      float iou_loss = (float)sy->sum_liou / cf;
      float cls_loss = (float)sy->sum_nll / cf;
      float obj_loss = (float)((0.75 * (double)obj_base + sy->obj_corr) / (double)NHW);
      out[0] = iou_loss;
      out[1] = obj_loss;
      out[2] = cls_loss;
      out[3] = iou_loss * 8.f + obj_loss * 16.f + cls_loss;
    }
  }
}

extern "C" void kernel_launch(void* const* d_in, const int* in_sizes, int n_in,
                              void* d_out, int out_size, void* d_ws, size_t ws_size,
                              hipStream_t stream) {
  const float* preds = (const float*)d_in[0];
  const float* targets = (const float*)d_in[1];
  int M = in_sizes[1] / 6;     // 4096
  int M4 = 4 * M;              // 16384

  char* ws = (char*)d_ws;
  Sync* sy = (Sync*)ws;                                 // 256 B
  size_t off = 256;
  int* winner = (int*)(ws + off);      off += (size_t)NHW * 4;   // 1.6 MB
  float* iou_arr = (float*)(ws + off); off += (size_t)M4 * 4;
  int* meta_arr = (int*)(ws + off);    off += (size_t)M4 * 4;
  float* pobj_arr = (float*)(ws + off); off += (size_t)M4 * 4;
  float* nll_arr = (float*)(ws + off);  off += (size_t)M4 * 4;
  float* part_obj = (float*)(ws + off); off += GRID1 * 4;
  float* part_iou = (float*)(ws + off); off += GRID1 * 4;
  float* part_cnt = (float*)(ws + off); off += GRID1 * 4;

  k1<<<GRID1, TB, 0, stream>>>(preds, targets, M, sy, winner,
                               iou_arr, meta_arr, pobj_arr, nll_arr,
                               part_obj, part_iou, part_cnt);
  k2<<<GRID2, TB, 0, stream>>>(sy, winner, iou_arr, meta_arr, pobj_arr, nll_arr,
                               part_obj, part_iou, part_cnt, M, (float*)d_out);
}